// Round 12
// baseline (245.445 us; speedup 1.0000x reference)
//
#include <hip/hip_runtime.h>
#include <hip/hip_fp16.h>

#define N_NODES 80000
#define N_EDGES 1280000
#define IN_CH 128
#define HID 64
#define OUT_CH 32

#define NBUCK 625       // 128 dst-nodes per bucket
#define CAP 3072        // bucket capacity
#define BIN_BLOCKS 1024 // 1250 edges per bin block

typedef float vf4 __attribute__((ext_vector_type(4)));
typedef short short8 __attribute__((ext_vector_type(8)));   // 8 bf16
typedef float floatx4 __attribute__((ext_vector_type(4)));  // MFMA acc

// ---- bf16 pack (RNE) for MFMA staging ----
__device__ __forceinline__ unsigned bf16rn(float x) {
    unsigned u = __float_as_uint(x);
    return (u + 0x7FFFu + ((u >> 16) & 1u)) >> 16;
}
__device__ __forceinline__ unsigned packbf2(float a, float b) {
    return bf16rn(a) | (bf16rn(b) << 16);
}
// ---- f16 pack/unpack for gather tables ----
__device__ __forceinline__ float hl(unsigned u) {
    return __half2float(__ushort_as_half((unsigned short)(u & 0xFFFFu)));
}
__device__ __forceinline__ float hh(unsigned u) {
    return __half2float(__ushort_as_half((unsigned short)(u >> 16)));
}
__device__ __forceinline__ unsigned pack2h(float a, float b) {
    return (unsigned)__half_as_ushort(__float2half_rn(a)) |
           ((unsigned)__half_as_ushort(__float2half_rn(b)) << 16);
}

// ---------------- fused K1: bin (blocks 0..1023) + MFMA GEMM1 (1024..2273) ----
// bin: packed word src | dstLocal<<17 into per-bucket arrays (1250 edges/block).
// GEMM1: h1[n][:] = x[n] @ W1 (UNSCALED), f16 table [N][64] ushort.
// 64-node tiles: LDS 34816 B -> 4 blocks/CU co-residency with bin blocks.
__global__ __launch_bounds__(256) void k_bin_gemm1(
        const int* __restrict__ src, const int* __restrict__ dst,
        int* __restrict__ gcur, unsigned int* __restrict__ binned,
        const float* __restrict__ x, const float* __restrict__ W1,
        unsigned short* __restrict__ h1h) {
    __shared__ unsigned short smem_u[17408];  // 34816 B
    int bid = blockIdx.x, t = threadIdx.x;
    if (bid < BIN_BLOCKS) {
        // ---- bin path (uses 5 KB of smem) ----
        int* hist = (int*)smem_u;
        int* lcur = hist + NBUCK;
        const int chunk = N_EDGES / BIN_BLOCKS;  // 1250
        int e0 = bid * chunk;
        int e1 = e0 + chunk;
        for (int i = t; i < NBUCK; i += 256) hist[i] = 0;
        __syncthreads();
        for (int e = e0 + t; e < e1; e += 256)
            atomicAdd(&hist[dst[e] >> 7], 1);
        __syncthreads();
        for (int i = t; i < NBUCK; i += 256) {
            int h = hist[i];
            lcur[i] = h ? atomicAdd(&gcur[i], h) : 0;
        }
        __syncthreads();
        for (int e = e0 + t; e < e1; e += 256) {
            int d = dst[e];
            int bk = d >> 7;
            int pos = atomicAdd(&lcur[bk], 1);
            if (pos < CAP)
                binned[(size_t)bk * CAP + pos] =
                    (unsigned int)src[e] | ((unsigned int)(d & 127) << 17);
        }
    } else {
        // ---- MFMA GEMM1: sX [64 nodes][136] bf16, sWT [64 cols][136] bf16 ----
        unsigned short* sX = smem_u;             // 64*136
        unsigned short* sWT = smem_u + 64 * 136; // 64*136
        long long nb = (long long)(bid - BIN_BLOCKS) * 64;
        // stage x -> bf16 (row-major, k contiguous): 2048 float4 loads
        for (int it = 0; it < 8; ++it) {
            int idx = t + it * 256;
            int node = idx >> 5, k4 = (idx & 31) * 4;
            float4 v = *(const float4*)&x[(nb + node) * IN_CH + k4];
            unsigned u0 = packbf2(v.x, v.y), u1 = packbf2(v.z, v.w);
            *(uint2*)&sX[node * 136 + k4] = (uint2){u0, u1};
        }
        // stage W1^T -> bf16 ([col][k]): 2048 float4 loads
        for (int it = 0; it < 8; ++it) {
            int idx = t + it * 256;
            int k = idx >> 4, c4 = (idx & 15) * 4;
            float4 w = *(const float4*)&W1[k * 64 + c4];
            sWT[(c4 + 0) * 136 + k] = (unsigned short)bf16rn(w.x);
            sWT[(c4 + 1) * 136 + k] = (unsigned short)bf16rn(w.y);
            sWT[(c4 + 2) * 136 + k] = (unsigned short)bf16rn(w.z);
            sWT[(c4 + 3) * 136 + k] = (unsigned short)bf16rn(w.w);
        }
        __syncthreads();
        int wv = t >> 6, lane = t & 63;
        int lm = lane & 15, q = lane >> 4;
        int m0 = wv * 16;
        floatx4 acc[4];
#pragma unroll
        for (int j = 0; j < 4; ++j) acc[j] = (floatx4){0.f, 0.f, 0.f, 0.f};
#pragma unroll
        for (int kk = 0; kk < 128; kk += 32) {
            short8 a = *(short8*)&sX[(m0 + lm) * 136 + kk + q * 8];
#pragma unroll
            for (int ct = 0; ct < 4; ++ct) {
                short8 bfr = *(short8*)&sWT[(ct * 16 + lm) * 136 + kk + q * 8];
                acc[ct] = __builtin_amdgcn_mfma_f32_16x16x32_bf16(a, bfr, acc[ct], 0, 0, 0);
            }
        }
        // D layout: col = lane&15, row = q*4 + reg
#pragma unroll
        for (int ct = 0; ct < 4; ++ct)
#pragma unroll
            for (int r = 0; r < 4; ++r) {
                long long node = nb + m0 + q * 4 + r;
                int c = ct * 16 + lm;
                h1h[node * 64 + c] = __half_as_ushort(__float2half_rn(acc[ct][r]));
            }
    }
}

// ---------------- K2: per-bucket counting sort -> CSR + dinv ----------------
__global__ __launch_bounds__(256) void k_csr(const unsigned int* __restrict__ binned,
                                             const int* __restrict__ cnt,
                                             int* __restrict__ csr,
                                             int* __restrict__ rs, int* __restrict__ re,
                                             float* __restrict__ dinv) {
    __shared__ int deg[128];
    __shared__ int scan[128];
    __shared__ int cur[128];
    int bk = blockIdx.x, t = threadIdx.x;
    int n_e = min(cnt[bk], CAP);
    const unsigned int* eb = binned + (size_t)bk * CAP;
    if (t < 128) deg[t] = 0;
    __syncthreads();
    for (int i = t; i < n_e; i += 256) atomicAdd(&deg[eb[i] >> 17], 1);
    __syncthreads();
    if (t < 128) scan[t] = deg[t];
    __syncthreads();
    for (int off = 1; off < 128; off <<= 1) {
        int v = (t < 128 && t >= off) ? scan[t - off] : 0;
        __syncthreads();
        if (t < 128) scan[t] += v;
        __syncthreads();
    }
    if (t < 128) {
        int incl = scan[t];
        int s = incl - deg[t];
        cur[t] = s;
        int n = bk * 128 + t;
        int base = bk * CAP;
        rs[n] = base + s;
        re[n] = base + incl;
        dinv[n] = rsqrtf((float)(deg[t] + 1));  // +1 self loop
    }
    __syncthreads();
    for (int i = t; i < n_e; i += 256) {
        unsigned int p = eb[i];
        int dL = p >> 17;
        int pos = atomicAdd(&cur[dL], 1);
        csr[bk * CAP + pos] = (int)(p & 0x1FFFF);
    }
}

// ---------------- agg layer 1 + shuffle-fused GEMM2 ----------------
// Wave per node: gather-sum dinv[s]*h1[s][:] (f16 table), shuffle-combine.
// Lanes 0..31 then hold the relu'd h2 row in registers; a 16-step shfl
// broadcast against f16-packed W2 (LDS) yields g2[n][:] directly (f16 packed).
// No per-node __syncthreads (waves uncoupled); h2 never touches global.
__global__ __launch_bounds__(256) void k_agg64g2(
        const unsigned int* __restrict__ h1u, const int* __restrict__ csr,
        const int* __restrict__ rs_, const int* __restrict__ re_,
        const float* __restrict__ dinv, const float* __restrict__ b1,
        const float* __restrict__ W2, unsigned int* __restrict__ g2u) {
    __shared__ unsigned int sW2[32 * 32];  // sW2[j*32+c] = f16pair(W2[2j][c], W2[2j+1][c])
    int t = threadIdx.x;
    for (int i = t; i < 1024; i += 256) {
        int j = i >> 5, c = i & 31;
        sW2[i] = pack2h(W2[(2 * j) * 32 + c], W2[(2 * j + 1) * 32 + c]);
    }
    __syncthreads();   // once, before gathers — no degree coupling
    int wv = t >> 6, lane = t & 63;
    int n = blockIdx.x * 4 + wv;
    int half = lane >> 5, fo = lane & 31;  // feats 2fo, 2fo+1
    int a = rs_[n], b = re_[n];
    float ax = 0.f, ay = 0.f;
    int e = a + half;
    for (; e + 6 < b; e += 8) {
        int s0 = csr[e], s1 = csr[e + 2], s2 = csr[e + 4], s3 = csr[e + 6];
        unsigned u0 = h1u[(size_t)s0 * 32 + fo]; float d0 = dinv[s0];
        unsigned u1 = h1u[(size_t)s1 * 32 + fo]; float d1 = dinv[s1];
        unsigned u2 = h1u[(size_t)s2 * 32 + fo]; float d2 = dinv[s2];
        unsigned u3 = h1u[(size_t)s3 * 32 + fo]; float d3 = dinv[s3];
        ax += d0 * hl(u0); ay += d0 * hh(u0);
        ax += d1 * hl(u1); ay += d1 * hh(u1);
        ax += d2 * hl(u2); ay += d2 * hh(u2);
        ax += d3 * hl(u3); ay += d3 * hh(u3);
    }
    for (; e < b; e += 2) {
        int s = csr[e];
        unsigned u = h1u[(size_t)s * 32 + fo];
        float d = dinv[s];
        ax += d * hl(u); ay += d * hh(u);
    }
    ax += __shfl_down(ax, 32);
    ay += __shfl_down(ay, 32);
    // lanes 0..31 now hold full neighbor sums for feats (2fo, 2fo+1)
    float dn = dinv[n];
    unsigned un = h1u[(size_t)n * 32 + fo];
    ax += dn * hl(un); ay += dn * hh(un);   // self loop
    float2 bb = *(const float2*)&b1[2 * fo];
    float hx = fmaxf(dn * ax + bb.x, 0.f);  // valid on lanes 0..31
    float hy = fmaxf(dn * ay + bb.y, 0.f);
    // GEMM2: col c = fo; j-range split across wave halves
    int jb = half * 16;
    float sum = 0.f;
#pragma unroll
    for (int i = 0; i < 16; ++i) {
        int j = jb + i;
        float h0 = __shfl(hx, j);           // sources lanes 0..31 only
        float h1v = __shfl(hy, j);
        unsigned w = sW2[j * 32 + fo];
        sum += h0 * hl(w) + h1v * hh(w);
    }
    sum += __shfl_down(sum, 32);            // lanes 0..31: full col sums
    float v0 = __shfl(sum, 2 * (lane & 15));
    float v1 = __shfl(sum, 2 * (lane & 15) + 1);
    if (lane < 16)
        g2u[(size_t)n * 16 + lane] = pack2h(v0, v1);
}

// ---------------- agg layer 2: F=32, f16 table ----------------
__global__ __launch_bounds__(256) void k_agg32(
        const unsigned int* __restrict__ g2u, const int* __restrict__ csr,
        const int* __restrict__ rs_, const int* __restrict__ re_,
        const float* __restrict__ dinv, const float* __restrict__ b2,
        float* __restrict__ outp) {
    int n = blockIdx.x * 4 + (threadIdx.x >> 6);
    int lane = threadIdx.x & 63;
    int oc = lane >> 3, fo = lane & 7;  // feats 4fo..4fo+3
    int a = rs_[n], b = re_[n];
    float ax = 0.f, ay = 0.f, az = 0.f, aw = 0.f;
    int e = a + oc;
    for (; e + 8 < b; e += 16) {
        int s0 = csr[e], s1 = csr[e + 8];
        uint2 u0 = *(const uint2*)&g2u[(size_t)s0 * 16 + 2 * fo]; float d0 = dinv[s0];
        uint2 u1 = *(const uint2*)&g2u[(size_t)s1 * 16 + 2 * fo]; float d1 = dinv[s1];
        ax += d0 * hl(u0.x); ay += d0 * hh(u0.x);
        az += d0 * hl(u0.y); aw += d0 * hh(u0.y);
        ax += d1 * hl(u1.x); ay += d1 * hh(u1.x);
        az += d1 * hl(u1.y); aw += d1 * hh(u1.y);
    }
    for (; e < b; e += 8) {
        int s = csr[e];
        uint2 u = *(const uint2*)&g2u[(size_t)s * 16 + 2 * fo];
        float d = dinv[s];
        ax += d * hl(u.x); ay += d * hh(u.x);
        az += d * hl(u.y); aw += d * hh(u.y);
    }
    ax += __shfl_down(ax, 32); ay += __shfl_down(ay, 32);
    az += __shfl_down(az, 32); aw += __shfl_down(aw, 32);
    ax += __shfl_down(ax, 16); ay += __shfl_down(ay, 16);
    az += __shfl_down(az, 16); aw += __shfl_down(aw, 16);
    ax += __shfl_down(ax, 8);  ay += __shfl_down(ay, 8);
    az += __shfl_down(az, 8);  aw += __shfl_down(aw, 8);
    if (oc == 0) {
        float dn = dinv[n];
        uint2 un = *(const uint2*)&g2u[(size_t)n * 16 + 2 * fo];
        ax += dn * hl(un.x); ay += dn * hh(un.x);
        az += dn * hl(un.y); aw += dn * hh(un.y);
        float4 bb = *(const float4*)&b2[4 * fo];
        vf4 o = {dn * ax + bb.x, dn * ay + bb.y, dn * az + bb.z, dn * aw + bb.w};
        __builtin_nontemporal_store(o, (vf4*)&outp[(size_t)n * 32 + 4 * fo]);
    }
}

static inline size_t align256(size_t x) { return (x + 255) & ~(size_t)255; }

extern "C" void kernel_launch(void* const* d_in, const int* in_sizes, int n_in,
                              void* d_out, int out_size, void* d_ws, size_t ws_size,
                              hipStream_t stream) {
    const float* x  = (const float*)d_in[0];
    const int*   ei = (const int*)d_in[1];
    const float* W1 = (const float*)d_in[2];
    const float* b1 = (const float*)d_in[3];
    const float* W2 = (const float*)d_in[4];
    const float* b2 = (const float*)d_in[5];
    float* out = (float*)d_out;

    const int* src = ei;
    const int* dst = ei + N_EDGES;

    // workspace layout (~32 MB, under proven 47 MB)
    char* ws = (char*)d_ws;
    size_t off = 0;
    int* gcur = (int*)(ws + off);              off = align256(off + NBUCK * 4);
    unsigned int* binned = (unsigned int*)(ws + off);
                                               off = align256(off + (size_t)NBUCK * CAP * 4);
    int* csr = (int*)(ws + off);               off = align256(off + (size_t)NBUCK * CAP * 4);
    int* rs  = (int*)(ws + off);               off = align256(off + (size_t)N_NODES * 4);
    int* re  = (int*)(ws + off);               off = align256(off + (size_t)N_NODES * 4);
    float* dinv = (float*)(ws + off);          off = align256(off + (size_t)N_NODES * 4);
    unsigned short* h1h = (unsigned short*)(ws + off);
                                               off = align256(off + (size_t)N_NODES * 64 * 2);
    unsigned int* g2u = (unsigned int*)(ws + off);  // separate: h1h read while g2u written
                                               off = align256(off + (size_t)N_NODES * 16 * 4);

    (void)hipMemsetAsync(gcur, 0, NBUCK * 4, stream);
    k_bin_gemm1<<<BIN_BLOCKS + N_NODES / 64, 256, 0, stream>>>(src, dst, gcur, binned,
                                                               x, W1, h1h);
    k_csr<<<NBUCK, 256, 0, stream>>>(binned, gcur, csr, rs, re, dinv);
    k_agg64g2<<<N_NODES / 4, 256, 0, stream>>>((const unsigned int*)h1h, csr, rs, re,
                                               dinv, b1, W2, g2u);
    k_agg32<<<N_NODES / 4, 256, 0, stream>>>(g2u, csr, rs, re, dinv, b2, out);
}